// Round 8
// baseline (11076.113 us; speedup 1.0000x reference)
//
#include <hip/hip_runtime.h>

// Problem constants (fixed by reference setup)
#define B_ 32
#define T_ 8192
#define I_ 16
#define H_ 128
#define P_ 1024
#define O_ 3
#define NB 16   // grid: 2 batch elements per block

typedef _Float16 h2 __attribute__((ext_vector_type(2)));
typedef _Float16 h4 __attribute__((ext_vector_type(4)));
typedef _Float16 h8 __attribute__((ext_vector_type(8)));

// v_dot2_f32_f16: 2-way f16 dot, fp32 accumulate
#if __has_builtin(__builtin_amdgcn_fdot2)
#define FDOT2(a, b, c) __builtin_amdgcn_fdot2((a), (b), (c), false)
#else
__device__ __forceinline__ float fdot2_asm(h2 a, h2 b, float c) {
    asm("v_dot2_f32_f16 %0, %1, %2, %0" : "+v"(c) : "v"(a), "v"(b));
    return c;
}
#define FDOT2(a, b, c) fdot2_asm((a), (b), (c))
#endif

// ---- macro machinery: (gate g 0..3, m 0..3, e 0..3) ------------------------
#define FORME(M, g) M(g,0,0) M(g,0,1) M(g,0,2) M(g,0,3) \
                    M(g,1,0) M(g,1,1) M(g,1,2) M(g,1,3) \
                    M(g,2,0) M(g,2,1) M(g,2,2) M(g,2,3) \
                    M(g,3,0) M(g,3,1) M(g,3,2) M(g,3,3)
#define FORALL(M) FORME(M,0) FORME(M,1) FORME(M,2) FORME(M,3)
#define FORG(M) M(0) M(1) M(2) M(3)

// DPP helpers (pure VALU cross-lane)
#define DPPF(v, ctrl) \
    __int_as_float(__builtin_amdgcn_mov_dpp(__float_as_int(v), (ctrl), 0xF, 0xF, true))
#define DPPI(v, ctrl) __builtin_amdgcn_mov_dpp((v), (ctrl), 0xF, 0xF, true)
// ds_swizzle xor-lane (BitMode): xor4=0x101F xor8=0x201F xor16=0x401F
#define SWZF(v, imm) \
    __int_as_float(__builtin_amdgcn_ds_swizzle(__float_as_int(v), (imm)))

__device__ __forceinline__ float tanh_f(float x) {
    return 2.f / (1.f + __expf(-2.f * x)) - 1.f;
}
__device__ __forceinline__ h4 cvt4(float4 v) {
    return (h4){(_Float16)v.x, (_Float16)v.y, (_Float16)v.z, (_Float16)v.w};
}

// LDS-only barrier (no vmcnt(0) drain; x-prefetch loads are consumed via
// register dependency so the compiler inserts its own vmcnt waits).
__device__ __forceinline__ void lds_barrier() {
    asm volatile("s_waitcnt lgkmcnt(0)\n\ts_barrier" ::: "memory");
}

// TWO batch elements per block, sharing one set of weight registers.
// 512 threads, thread = (j, kc): j=unit 0..127, kc=quad lane 0..3.
// Per batch: thread covers 4 gate rows {g*128+j} x interleaved h-subset
// {kc*8+32m+e} (conflict-free broadcast b128 reads). Chains A and B are
// independent -> their latency chains (LDS reads, exp, DPP) overlap.
// FC reduction: the VERIFIED R6 xor-butterfly (R7's row_shr variant put row
// sums in top lanes while bottom lanes wrote — 2/16 of the sum; reverted).
__global__ __launch_bounds__(512, 2)
void lstm_fused(
    const float* __restrict__ x,      // [B,T,16]
    const float* __restrict__ W_ih,   // [512,16]
    const float* __restrict__ W_hh,   // [512,128]
    const float* __restrict__ b_ih,   // [512]
    const float* __restrict__ b_hh,   // [512]
    const float* __restrict__ W_fc,   // [3,128]
    float* __restrict__ sums)         // [B,P,3]  (fully overwritten per block)
{
    const int blk  = blockIdx.x;
    const int tid  = threadIdx.x;
    const int lane = tid & 63;
    const int j    = tid >> 2;
    const int kc   = tid & 3;
    const int bA   = blk;
    const int bB   = blk + NB;

    __shared__ __align__(16) _Float16 hhA[2][H_];
    __shared__ __align__(16) _Float16 hhB[2][H_];
    __shared__ __align__(16) _Float16 xtA[2][16 * I_];
    __shared__ __align__(16) _Float16 xtB[2][16 * I_];
    __shared__ float sumsA_lds[P_ * O_];   // 12 KB
    __shared__ float sumsB_lds[P_ * O_];   // 12 KB

    // ---- weights -> f16 half2 named scalars (72 VGPRs), shared by A and B --
    const float* wr0 = W_hh + (0 * H_ + j) * H_;
    const float* wr1 = W_hh + (1 * H_ + j) * H_;
    const float* wr2 = W_hh + (2 * H_ + j) * H_;
    const float* wr3 = W_hh + (3 * H_ + j) * H_;
    #define WLOAD(g, m, e) h2 W##g##_##m##_##e = (h2){ \
        (_Float16)wr##g[kc * 8 + 32 * (m) + 2 * (e)], \
        (_Float16)wr##g[kc * 8 + 32 * (m) + 2 * (e) + 1]};
    FORALL(WLOAD)
    #define ULOAD(g) \
        h2 U##g##_0 = (h2){(_Float16)W_ih[((g) * H_ + j) * I_ + kc * 4 + 0], \
                           (_Float16)W_ih[((g) * H_ + j) * I_ + kc * 4 + 1]}; \
        h2 U##g##_1 = (h2){(_Float16)W_ih[((g) * H_ + j) * I_ + kc * 4 + 2], \
                           (_Float16)W_ih[((g) * H_ + j) * I_ + kc * 4 + 3]};
    FORG(ULOAD)

    const float bias = b_ih[kc * H_ + j] + b_hh[kc * H_ + j];
    const float wfc  = (kc < 3) ? W_fc[kc * H_ + j] : 0.f;

    // ---- init LDS ----
    for (int i = tid; i < P_ * O_; i += 512) { sumsA_lds[i] = 0.f; sumsB_lds[i] = 0.f; }
    if (tid < H_) { hhA[0][tid] = (_Float16)0.f; hhB[0][tid] = (_Float16)0.f; }

    const float* xbA = x + (size_t)bA * T_ * I_;
    const float* xbB = x + (size_t)bB * T_ * I_;
    float4 xr4 = make_float4(0.f, 0.f, 0.f, 0.f);
    const int wv = tid >> 6;
    if (wv == 0) { xr4 = ((const float4*)xbA)[lane]; *(h4*)&xtA[0][lane * 4] = cvt4(xr4); }
    if (wv == 1) { xr4 = ((const float4*)xbB)[lane]; *(h4*)&xtB[0][lane * 4] = cvt4(xr4); }
    float cA = 0.f, cB = 0.f;
    __syncthreads();

    #pragma unroll 1
    for (int t = 0; t < T_; ++t) {
        const int off = t & 15;
        const int btx = (t >> 4) & 1;
        const int bh  = t & 1;

        // x prefetch: wave0 streams batch A, wave1 batch B (wave-uniform)
        if (wv == 0) {
            if (off == 0 && t + 16 < T_) xr4 = ((const float4*)(xbA + (t + 16) * I_))[lane];
            if (off == 8 && t + 8 < T_)  *(h4*)&xtA[btx ^ 1][lane * 4] = cvt4(xr4);
        } else if (wv == 1) {
            if (off == 0 && t + 16 < T_) xr4 = ((const float4*)(xbB + (t + 16) * I_))[lane];
            if (off == 8 && t + 8 < T_)  *(h4*)&xtB[btx ^ 1][lane * 4] = cvt4(xr4);
        }

        const h4 xA4 = *(const h4*)&xtA[btx][off * I_ + kc * 4];
        const h4 xB4 = *(const h4*)&xtB[btx][off * I_ + kc * 4];
        const h2 xA0 = __builtin_shufflevector(xA4, xA4, 0, 1);
        const h2 xA1 = __builtin_shufflevector(xA4, xA4, 2, 3);
        const h2 xB0 = __builtin_shufflevector(xB4, xB4, 0, 1);
        const h2 xB1 = __builtin_shufflevector(xB4, xB4, 2, 3);
        // photo id: kc==0 lanes hold channel 2 in xX4[2]; quad-broadcast it
        int idA = (int)(float)xA4[2]; idA = DPPI(idA, 0x00);
        int idB = (int)(float)xB4[2]; idB = DPPI(idB, 0x00);

        // dual-chain gate partials (independent -> latency overlap)
        float a0A = 0.f, a1A = 0.f, a2A = 0.f, a3A = 0.f;
        float a0B = 0.f, a1B = 0.f, a2B = 0.f, a3B = 0.f;
        #define HD2(m) { \
            h8 hA = *(const h8*)&hhA[bh][kc * 8 + 32 * (m)]; \
            h8 hB = *(const h8*)&hhB[bh][kc * 8 + 32 * (m)]; \
            h2 pA0 = __builtin_shufflevector(hA, hA, 0, 1); \
            h2 pA1 = __builtin_shufflevector(hA, hA, 2, 3); \
            h2 pA2 = __builtin_shufflevector(hA, hA, 4, 5); \
            h2 pA3 = __builtin_shufflevector(hA, hA, 6, 7); \
            h2 pB0 = __builtin_shufflevector(hB, hB, 0, 1); \
            h2 pB1 = __builtin_shufflevector(hB, hB, 2, 3); \
            h2 pB2 = __builtin_shufflevector(hB, hB, 4, 5); \
            h2 pB3 = __builtin_shufflevector(hB, hB, 6, 7); \
            a0A = FDOT2(pA0, W0_##m##_0, a0A); a0A = FDOT2(pA1, W0_##m##_1, a0A); \
            a0A = FDOT2(pA2, W0_##m##_2, a0A); a0A = FDOT2(pA3, W0_##m##_3, a0A); \
            a1A = FDOT2(pA0, W1_##m##_0, a1A); a1A = FDOT2(pA1, W1_##m##_1, a1A); \
            a1A = FDOT2(pA2, W1_##m##_2, a1A); a1A = FDOT2(pA3, W1_##m##_3, a1A); \
            a2A = FDOT2(pA0, W2_##m##_0, a2A); a2A = FDOT2(pA1, W2_##m##_1, a2A); \
            a2A = FDOT2(pA2, W2_##m##_2, a2A); a2A = FDOT2(pA3, W2_##m##_3, a2A); \
            a3A = FDOT2(pA0, W3_##m##_0, a3A); a3A = FDOT2(pA1, W3_##m##_1, a3A); \
            a3A = FDOT2(pA2, W3_##m##_2, a3A); a3A = FDOT2(pA3, W3_##m##_3, a3A); \
            a0B = FDOT2(pB0, W0_##m##_0, a0B); a0B = FDOT2(pB1, W0_##m##_1, a0B); \
            a0B = FDOT2(pB2, W0_##m##_2, a0B); a0B = FDOT2(pB3, W0_##m##_3, a0B); \
            a1B = FDOT2(pB0, W1_##m##_0, a1B); a1B = FDOT2(pB1, W1_##m##_1, a1B); \
            a1B = FDOT2(pB2, W1_##m##_2, a1B); a1B = FDOT2(pB3, W1_##m##_3, a1B); \
            a2B = FDOT2(pB0, W2_##m##_0, a2B); a2B = FDOT2(pB1, W2_##m##_1, a2B); \
            a2B = FDOT2(pB2, W2_##m##_2, a2B); a2B = FDOT2(pB3, W2_##m##_3, a2B); \
            a3B = FDOT2(pB0, W3_##m##_0, a3B); a3B = FDOT2(pB1, W3_##m##_1, a3B); \
            a3B = FDOT2(pB2, W3_##m##_2, a3B); a3B = FDOT2(pB3, W3_##m##_3, a3B); }
        HD2(0) HD2(1) HD2(2) HD2(3)
        a0A = FDOT2(xA0, U0_0, a0A); a0A = FDOT2(xA1, U0_1, a0A);
        a1A = FDOT2(xA0, U1_0, a1A); a1A = FDOT2(xA1, U1_1, a1A);
        a2A = FDOT2(xA0, U2_0, a2A); a2A = FDOT2(xA1, U2_1, a2A);
        a3A = FDOT2(xA0, U3_0, a3A); a3A = FDOT2(xA1, U3_1, a3A);
        a0B = FDOT2(xB0, U0_0, a0B); a0B = FDOT2(xB1, U0_1, a0B);
        a1B = FDOT2(xB0, U1_0, a1B); a1B = FDOT2(xB1, U1_1, a1B);
        a2B = FDOT2(xB0, U2_0, a2B); a2B = FDOT2(xB1, U2_1, a2B);
        a3B = FDOT2(xB0, U3_0, a3B); a3B = FDOT2(xB1, U3_1, a3B);

        // quad butterflies (xor1=0xB1, xor2=0x4E); A/B chains interleave
        float s_;
        s_ = DPPF(a0A, 0xB1); a0A += s_;  s_ = DPPF(a0B, 0xB1); a0B += s_;
        s_ = DPPF(a1A, 0xB1); a1A += s_;  s_ = DPPF(a1B, 0xB1); a1B += s_;
        s_ = DPPF(a2A, 0xB1); a2A += s_;  s_ = DPPF(a2B, 0xB1); a2B += s_;
        s_ = DPPF(a3A, 0xB1); a3A += s_;  s_ = DPPF(a3B, 0xB1); a3B += s_;
        s_ = DPPF(a0A, 0x4E); a0A += s_;  s_ = DPPF(a0B, 0x4E); a0B += s_;
        s_ = DPPF(a1A, 0x4E); a1A += s_;  s_ = DPPF(a1B, 0x4E); a1B += s_;
        s_ = DPPF(a2A, 0x4E); a2A += s_;  s_ = DPPF(a2B, 0x4E); a2B += s_;
        s_ = DPPF(a3A, 0x4E); a3A += s_;  s_ = DPPF(a3B, 0x4E); a3B += s_;

        // lane kc activates gate kc (i,f,o sigmoid; kc==2 tanh)
        const bool isg = (kc == 2);
        float tgA = (kc == 0) ? a0A : (kc == 1) ? a1A : (kc == 2) ? a2A : a3A;
        float tgB = (kc == 0) ? a0B : (kc == 1) ? a1B : (kc == 2) ? a2B : a3B;
        tgA += bias; tgB += bias;
        const float argA = isg ? (tgA + tgA) : tgA;
        const float argB = isg ? (tgB + tgB) : tgB;
        const float sfA = 1.f / (1.f + __expf(-argA));
        const float sfB = 1.f / (1.f + __expf(-argB));
        const float actA = isg ? (sfA + sfA - 1.f) : sfA;
        const float actB = isg ? (sfB + sfB - 1.f) : sfB;

        const float giA = DPPF(actA, 0x00), giB = DPPF(actB, 0x00);
        const float gfA = DPPF(actA, 0x55), gfB = DPPF(actB, 0x55);
        const float ggA = DPPF(actA, 0xAA), ggB = DPPF(actB, 0xAA);
        const float goA = DPPF(actA, 0xFF), goB = DPPF(actB, 0xFF);
        cA = fmaf(gfA, cA, giA * ggA);
        cB = fmaf(gfB, cB, giB * ggB);
        const float hnA = goA * tanh_f(cA);
        const float hnB = goB * tanh_f(cB);

        if (kc == 0) { hhA[bh ^ 1][j] = (_Float16)hnA; hhB[bh ^ 1][j] = (_Float16)hnB; }

        // fused FC + segment accumulate — VERIFIED R6 xor-butterfly:
        // xor4/xor8/xor16 swizzles + xor32 shfl sum the 16 j per kc;
        // lanes 0,1,2 of each wave then hold the o=0,1,2 sums.
        float pA = hnA * wfc;
        float pB = hnB * wfc;
        pA += SWZF(pA, 0x101F);  pB += SWZF(pB, 0x101F);
        pA += SWZF(pA, 0x201F);  pB += SWZF(pB, 0x201F);
        pA += SWZF(pA, 0x401F);  pB += SWZF(pB, 0x401F);
        pA += __shfl_xor(pA, 32, 64);
        pB += __shfl_xor(pB, 32, 64);
        const bool red = (lane < 3);
        if (red && (unsigned)idA < P_) atomicAdd(&sumsA_lds[idA * O_ + lane], pA);
        if (red && (unsigned)idB < P_) atomicAdd(&sumsB_lds[idB * O_ + lane], pB);

        lds_barrier();   // single barrier per iter covers both chains
    }

    __syncthreads();
    // ---- writeback (block owns slices bA and bB exclusively) ----
    float* sgA = sums + (size_t)bA * P_ * O_;
    float* sgB = sums + (size_t)bB * P_ * O_;
    for (int i = tid; i < P_ * O_; i += 512) { sgA[i] = sumsA_lds[i]; sgB[i] = sumsB_lds[i]; }
}

// per-(b,p) occurrence counts — embarrassingly parallel, off the serial loop
__global__ void count_kernel(const float* __restrict__ x,
                             float* __restrict__ counts)
{
    const int b = blockIdx.x;
    __shared__ int cnt[P_];
    for (int i = threadIdx.x; i < P_; i += 256) cnt[i] = 0;
    __syncthreads();
    const float* xb = x + (size_t)b * T_ * I_;
    for (int t = threadIdx.x; t < T_; t += 256) {
        const int id = (int)xb[t * I_ + 2];
        if ((unsigned)id < P_) atomicAdd(&cnt[id], 1);
    }
    __syncthreads();
    for (int i = threadIdx.x; i < P_; i += 256)
        counts[b * P_ + i] = (float)cnt[i];
}

// out[b,p,o] = (sums[b,p,o] + cnt*b_fc[o]) / max(cnt,1)
__global__ void finalize_kernel(const float* __restrict__ sums,
                                const float* __restrict__ counts,
                                const float* __restrict__ b_fc,
                                float* __restrict__ out)
{
    const int idx = blockIdx.x * blockDim.x + threadIdx.x;
    if (idx >= B_ * P_ * O_) return;
    const int o  = idx % O_;
    const int bp = idx / O_;
    const float cnt = counts[bp];
    const float denom = (cnt > 0.f) ? cnt : 1.f;
    out[idx] = (sums[idx] + cnt * b_fc[o]) / denom;
}

extern "C" void kernel_launch(void* const* d_in, const int* in_sizes, int n_in,
                              void* d_out, int out_size, void* d_ws, size_t ws_size,
                              hipStream_t stream) {
    const float* x    = (const float*)d_in[0];
    const float* W_ih = (const float*)d_in[1];
    const float* W_hh = (const float*)d_in[2];
    const float* b_ih = (const float*)d_in[3];
    const float* b_hh = (const float*)d_in[4];
    const float* W_fc = (const float*)d_in[5];
    const float* b_fc = (const float*)d_in[6];
    // d_in[7] = num_photos (==P_, fixed by the problem)

    float* out    = (float*)d_out;
    float* sums   = (float*)d_ws;                 // B*P*3 floats
    float* counts = sums + (size_t)B_ * P_ * O_;  // B*P floats
    // sums/counts fully overwritten by the kernels — no memset needed.

    lstm_fused<<<NB, 512, 0, stream>>>(x, W_ih, W_hh, b_ih, b_hh, W_fc, sums);
    count_kernel<<<B_, 256, 0, stream>>>(x, counts);

    const int n = B_ * P_ * O_;
    finalize_kernel<<<(n + 255) / 256, 256, 0, stream>>>(sums, counts, b_fc, out);
}